// Round 16
// baseline (85.535 us; speedup 1.0000x reference)
//
#include <hip/hip_runtime.h>

// Deformable conv2d (N=4, C=OC=256, 80x80, 3x3, s1 p1 d1):
// fused bilinear-im2col + bf16 MFMA GEMM, fp32 accumulate.
// R16: de-phasing attack on the sum-of-floors serialization (R15 post-mortem:
//   wall ~= VALU+LDS+MFMA+TA floors; 8-wave blocks are barrier-phase-locked
//   and 112 CUs hold only one block).
//   - 800 blocks x 256 thr (4 waves, PT=32): per-wave oc-span 64 (LDS B-read
//     per px halves); ~110 VGPR -> 3-4 independently-phased blocks/CU fill
//     each other's idle pipes.
//   - FINISH on float2 (ffp-contract -> v_pk_fma_f32): ~13 ops/dword vs 17.
//   All R12-R15 verified mechanisms retained: NHWC xt, channel-low coalesced
//   gathers, XCD swizzle, PREFA-before-ISSUE, cvt_pk pack, setprio, BARRIER_LDS.

typedef short short8 __attribute__((ext_vector_type(8)));
typedef float floatx4 __attribute__((ext_vector_type(4)));
typedef float floatx2 __attribute__((ext_vector_type(2)));
typedef unsigned int uint4v __attribute__((ext_vector_type(4)));

#define Cc    256
#define OCc   256
#define Hh    80
#define Ww    80
#define HW    6400
#define KK    9
#define Ktot  2304
#define PT    32            // pixels per block
#define KC    64            // K per chunk = one tap x 64 channels
#define NCHUNK (Ktot / KC)  // 36
#define NKB   (Ktot / 32)   // 72
#define WP_ELEMS (Ktot * OCc)          // 589824 ushorts (1.18 MB)
#define XT_OFF   ((size_t)WP_ELEMS)

// Relaxed barrier: retire LDS ops; vmem loads stay in flight.
#define BARRIER_LDS()                                      \
  do {                                                     \
    asm volatile("s_waitcnt lgkmcnt(0)" ::: "memory");     \
    __builtin_amdgcn_s_barrier();                          \
  } while (0)

__device__ __forceinline__ unsigned short f2bf(float f) {
  unsigned u = __float_as_uint(f);
  u += 0x7FFF + ((u >> 16) & 1);
  return (unsigned short)(u >> 16);
}
// lo16 = bf16(lo), hi16 = bf16(hi)  (RNE; verified)
__device__ __forceinline__ unsigned int cvtpk(float lo, float hi) {
  unsigned int r;
  asm("v_cvt_pk_bf16_f32 %0, %1, %2" : "=v"(r) : "v"(lo), "v"(hi));
  return r;
}

// ---- Kernel 1: weight fp32 -> bf16 A-fragments, tap-major K (k'=tap*256+c) --
__global__ void pack_weight(const float* __restrict__ w,
                            unsigned short* __restrict__ wp) {
  const int t = blockIdx.x * 256 + threadIdx.x;   // 73728 threads
  const int lane = t & 63;
  const int ocf  = (t >> 6) & 15;
  const int kb   = t >> 10;
  const int oc   = ocf * 16 + (lane & 15);
  const int k0   = kb * 32 + (lane >> 4) * 8;     // 8 consecutive k'
  const int tap  = k0 >> 8;
  const int c0   = k0 & 255;
  const float* src = w + (size_t)oc * Ktot + (size_t)c0 * KK + tap;
  short8 pk;
  #pragma unroll
  for (int e = 0; e < 8; ++e) pk[e] = (short)f2bf(src[e * KK]);
  *(short8*)(wp + (size_t)t * 8) = pk;
}

// ---- Kernel 2: x NCHW fp32 -> NHWC bf16 (xt[n][hw][c]) ----
__global__ void nhwc_pack(const float* __restrict__ x,
                          unsigned short* __restrict__ xt) {
  __shared__ float tile[64][65];
  const int tid = threadIdx.x;
  const int hw0 = blockIdx.x * 64;
  const int c0  = blockIdx.y * 64;
  const int n   = blockIdx.z;
  #pragma unroll
  for (int i = 0; i < 16; ++i) {
    const int idx = i * 256 + tid;
    const int cl = idx >> 6, hl = idx & 63;
    tile[cl][hl] = x[((size_t)(n * Cc + c0 + cl)) * HW + hw0 + hl];
  }
  __syncthreads();
  #pragma unroll
  for (int i = 0; i < 16; ++i) {
    const int idx = i * 256 + tid;
    const int hl = idx >> 6, cl = idx & 63;
    xt[((size_t)(n * HW + hw0 + hl)) * Cc + c0 + cl] = f2bf(tile[cl][hl]);
  }
}

// ---- Kernel 3: fused sampling + MFMA, 4 waves / 32 px per block ----
__global__ __launch_bounds__(256, 4) void dcn_mfma(
    const float* __restrict__ x, const float* __restrict__ offset,
    const unsigned short* __restrict__ wp,
    const unsigned short* __restrict__ xt, float* __restrict__ out) {
  __shared__ unsigned short s_col[3][PT * KC];  // 3 x 4KB, XOR-swizzled [px][k]
  __shared__ float4 s_w[KK * PT];               // masked corner weights (4.6KB)
  __shared__ int4   s_i[KK * PT];               // corner byte offsets   (4.6KB)

  const int tid  = threadIdx.x;
  const int lane = tid & 63;
  const int wv   = tid >> 6;        // 4 waves; wave owns ocf [wv*4, wv*4+4)

  // XCD-aware bijective swizzle: 800 blocks = 8 XCDs x 100 contiguous tiles
  const int bid  = blockIdx.x;
  const int logical = (bid & 7) * 100 + (bid >> 3);
  const int nn   = logical / 200;
  const int tile = logical - nn * 200;
  const int p0   = tile * PT;
  const char* xn = (const char*)(xt + (size_t)nn * HW * Cc);

  // ---- Phase 0: bilinear coords; masks folded into per-corner weights ----
  for (int s = tid; s < KK * PT; s += 256) {
    const int k = s / PT, p = s % PT;
    const int pp = p0 + p;
    const int oy = pp / Ww, ox = pp % Ww;
    const int ky = k / 3, kx = k % 3;
    const float offy = offset[(size_t)(nn * 18 + 2 * k    ) * HW + pp];
    const float offx = offset[(size_t)(nn * 18 + 2 * k + 1) * HW + pp];
    const float py = offy + (float)(ky + oy - 1);
    const float px = offx + (float)(kx + ox - 1);
    const float fy0 = floorf(py), fx0 = floorf(px);
    const int iy0 = (int)fy0, ix0 = (int)fx0;
    const float wy1 = py - fy0, wx1 = px - fx0;
    const float wy0 = 1.f - wy1, wx0 = 1.f - wx1;
    const bool my0 = (iy0     >= 0) & (iy0     < Hh);
    const bool my1 = (iy0 + 1 >= 0) & (iy0 + 1 < Hh);
    const bool mx0 = (ix0     >= 0) & (ix0     < Ww);
    const bool mx1 = (ix0 + 1 >= 0) & (ix0 + 1 < Ww);
    const int cy0 = min(max(iy0,     0), Hh - 1);
    const int cy1 = min(max(iy0 + 1, 0), Hh - 1);
    const int cx0 = min(max(ix0,     0), Ww - 1);
    const int cx1 = min(max(ix0 + 1, 0), Ww - 1);
    float4 w4;
    w4.x = wx0 * wy0 * ((my0 && mx0) ? 1.f : 0.f);
    w4.y = wx1 * wy0 * ((my0 && mx1) ? 1.f : 0.f);
    w4.z = wx0 * wy1 * ((my1 && mx0) ? 1.f : 0.f);
    w4.w = wx1 * wy1 * ((my1 && mx1) ? 1.f : 0.f);
    int4 i4;  // byte offsets into xt[n]: hw * 256ch * 2B
    i4.x = (cy0 * Ww + cx0) * 512;  i4.y = (cy0 * Ww + cx1) * 512;
    i4.z = (cy1 * Ww + cx0) * 512;  i4.w = (cy1 * Ww + cx1) * 512;
    s_w[s] = w4;
    s_i[s] = i4;
  }

  floatx4 acc[4][2] = {};           // 4 ocf x 2 px-frags
  const int lm = lane & 15, lg = lane >> 4;
  // Coalesced sampling map (R12): cg in low 3 lane bits.
  const int spx = tid >> 3;         // sampling pixel (0..31)
  const int cg  = tid & 7;          // channel group: 8 channels
  const int wbyte = spx * 128 + ((cg * 16) ^ ((spx & 7) << 4));
  __syncthreads();                  // once; full drain fine here

  // Named in-flight register sets (rule #20: static indices only).
  short8 raA, rbA, rcA, rdA, raB, rbB, rcB, rdB;  // gathers (2 sets, 16 VGPR ea)
  short8 fA[2][4], fB[2][4];                      // A-frags [ks][f] (2 sets, 32 ea)

  #define ISSUE(ch, S)                                                  \
    { const int tap_ = (ch) >> 2;                                       \
      const int coff_ = (((ch) & 3) * KC + cg * 8) * 2;                 \
      const int4 i4_ = s_i[tap_ * PT + spx];                            \
      ra##S = *(const short8*)(xn + i4_.x + coff_);                     \
      rb##S = *(const short8*)(xn + i4_.y + coff_);                     \
      rc##S = *(const short8*)(xn + i4_.z + coff_);                     \
      rd##S = *(const short8*)(xn + i4_.w + coff_); }

  // Prefetch chunk ch's 8 A-fragments (4 ocf x 2 ks) into set S.
  #define PREFA(ch, S)                                                  \
    { _Pragma("unroll")                                                 \
      for (int ks_ = 0; ks_ < 2; ++ks_) {                               \
        const unsigned short* w0_ = wp                                  \
            + (size_t)((ch) * 2 + ks_) * (16 * 64 * 8)                  \
            + (size_t)((wv * 4) * 64 + lane) * 8;                       \
        _Pragma("unroll")                                               \
        for (int f_ = 0; f_ < 4; ++f_)                                  \
          f##S[ks_][f_] = *(const short8*)(w0_ + (size_t)f_ * 64 * 8);  \
      } }

  // float2 bilinear combine (-> v_pk_fma_f32 via ffp-contract) + cvt_pk pack.
  #define FINISH(ch, S)                                                 \
    { const int tap_ = (ch) >> 2;                                       \
      const float4 w4_ = s_w[tap_ * PT + spx];                          \
      const uint4v ua_ = __builtin_bit_cast(uint4v, ra##S);             \
      const uint4v ub_ = __builtin_bit_cast(uint4v, rb##S);             \
      const uint4v uc_ = __builtin_bit_cast(uint4v, rc##S);             \
      const uint4v ud_ = __builtin_bit_cast(uint4v, rd##S);             \
      uint4v pk_;                                                       \
      _Pragma("unroll")                                                 \
      for (int r_ = 0; r_ < 4; ++r_) {                                  \
        floatx2 va_, vb_, vc_, vd_;                                     \
        va_[0] = __uint_as_float(ua_[r_] << 16);                        \
        va_[1] = __uint_as_float(ua_[r_] & 0xFFFF0000u);                \
        vb_[0] = __uint_as_float(ub_[r_] << 16);                        \
        vb_[1] = __uint_as_float(ub_[r_] & 0xFFFF0000u);                \
        vc_[0] = __uint_as_float(uc_[r_] << 16);                        \
        vc_[1] = __uint_as_float(uc_[r_] & 0xFFFF0000u);                \
        vd_[0] = __uint_as_float(ud_[r_] << 16);                        \
        vd_[1] = __uint_as_float(ud_[r_] & 0xFFFF0000u);                \
        const floatx2 v_ = w4_.x * va_ + w4_.y * vb_                    \
                         + w4_.z * vc_ + w4_.w * vd_;                   \
        pk_[r_] = cvtpk(v_[0], v_[1]);                                  \
      }                                                                 \
      *(uint4v*)((char*)s_col[(ch) % 3] + wbyte) = pk_; }

  // Pure ds_read + MFMA (A-frags preloaded in set S) + T5 setprio.
  #define MFMA_STEP(ch, S)                                              \
    { const char* base_ = (const char*)s_col[(ch) % 3];                 \
      __builtin_amdgcn_s_setprio(1);                                    \
      _Pragma("unroll")                                                 \
      for (int ks_ = 0; ks_ < 2; ++ks_) {                               \
        short8 b_[2];                                                   \
        _Pragma("unroll")                                               \
        for (int j_ = 0; j_ < 2; ++j_) {                                \
          const int px_ = j_ * 16 + lm;                                 \
          const int byte_ = px_ * 128 + (((ks_ * 64) + lg * 16) ^ ((px_ & 7) << 4)); \
          b_[j_] = *(const short8*)(base_ + byte_);                     \
        }                                                               \
        _Pragma("unroll")                                               \
        for (int f_ = 0; f_ < 4; ++f_) {                                \
          _Pragma("unroll")                                             \
          for (int j_ = 0; j_ < 2; ++j_)                                \
            acc[f_][j_] = __builtin_amdgcn_mfma_f32_16x16x32_bf16(      \
                f##S[ks_][f_], b_[j_], acc[f_][j_], 0, 0, 0);           \
        }                                                               \
      }                                                                 \
      __builtin_amdgcn_s_setprio(0); }

  // ---- Prologue: buf0 + A-frags(0) ready; gathers(1) in flight ----
  PREFA(0, A);
  ISSUE(0, A);
  FINISH(0, A);          // startup stall (once)
  ISSUE(1, A);
  BARRIER_LDS();

  // ---- Main loop (2 chunks/iter) ----
  for (int it = 0; it < NCHUNK / 2; ++it) {
    const int ch = it * 2;
    MFMA_STEP(ch, A);
    PREFA(ch + 1, B);
    if (ch + 2 < NCHUNK) ISSUE(ch + 2, B);
    FINISH(ch + 1, A);   // gathers issued a full chunk ago
    BARRIER_LDS();
    MFMA_STEP(ch + 1, B);
    if (ch + 2 < NCHUNK) PREFA(ch + 2, A);
    if (ch + 3 < NCHUNK) ISSUE(ch + 3, A);
    if (ch + 2 < NCHUNK) FINISH(ch + 2, B);
    BARRIER_LDS();
  }

  // ---- Epilogue: direct stores; C/D col(px)=lane&15, row(oc)=lg*4+r ----
  #pragma unroll
  for (int f = 0; f < 4; ++f) {
    const int oc = (wv * 4 + f) * 16 + lg * 4;
    #pragma unroll
    for (int j = 0; j < 2; ++j) {
      const int px = p0 + j * 16 + lm;
      #pragma unroll
      for (int r = 0; r < 4; ++r) {
        out[(size_t)(nn * OCc + oc + r) * HW + px] = acc[f][j][r];
      }
    }
  }
}

extern "C" void kernel_launch(void* const* d_in, const int* in_sizes, int n_in,
                              void* d_out, int out_size, void* d_ws, size_t ws_size,
                              hipStream_t stream) {
  const float* x      = (const float*)d_in[0];
  const float* offset = (const float*)d_in[1];
  const float* weight = (const float*)d_in[2];
  float* out = (float*)d_out;
  unsigned short* wp = (unsigned short*)d_ws;              // 1.18 MB
  unsigned short* xt = (unsigned short*)d_ws + XT_OFF;     // 13.1 MB

  pack_weight<<<dim3(NKB * 16 * 64 / 256), dim3(256), 0, stream>>>(weight, wp);
  nhwc_pack<<<dim3(HW / 64, Cc / 64, 4), dim3(256), 0, stream>>>(x, xt);
  dcn_mfma<<<dim3(800), dim3(256), 0, stream>>>(x, offset, wp, xt, out);
}

// Round 17
// 65.374 us; speedup vs baseline: 1.3084x; 1.3084x over previous
//
#include <hip/hip_runtime.h>

// Deformable conv2d (N=4, C=OC=256, 80x80, 3x3, s1 p1 d1):
// fused bilinear-im2col + bf16 MFMA GEMM, fp32 accumulate.
// R17 = R15 (best verified: 400x512 PT=64, NHWC xt, channel-low coalesced
//   gathers, XCD swizzle, PREFA-before-ISSUE, triple-buffer slab, cvt_pk)
//   + R16's correctness-verified float2 packed FINISH (v_pk_fma via
//     ffp-contract; ~25% fewer FINISH VALU ops)
//   + prep kernels merged into one launch (block-range partition).
//   R16's 4-wave structure reverted (regressed 24%: grid-limited occupancy
//   + doubled A-traffic).

typedef short short8 __attribute__((ext_vector_type(8)));
typedef float floatx4 __attribute__((ext_vector_type(4)));
typedef float floatx2 __attribute__((ext_vector_type(2)));
typedef unsigned int uint4v __attribute__((ext_vector_type(4)));

#define Cc    256
#define OCc   256
#define Hh    80
#define Ww    80
#define HW    6400
#define KK    9
#define Ktot  2304
#define PT    64            // pixels per block
#define KC    64            // K per chunk = one tap x 64 channels
#define NCHUNK (Ktot / KC)  // 36
#define NKB   (Ktot / 32)   // 72
#define WP_ELEMS (Ktot * OCc)          // 589824 ushorts (1.18 MB)
#define XT_OFF   ((size_t)WP_ELEMS)
#define PREP_W_BLOCKS 288              // 73728 threads / 256

// Relaxed barrier: retire LDS ops; vmem loads stay in flight.
#define BARRIER_LDS()                                      \
  do {                                                     \
    asm volatile("s_waitcnt lgkmcnt(0)" ::: "memory");     \
    __builtin_amdgcn_s_barrier();                          \
  } while (0)

__device__ __forceinline__ unsigned short f2bf(float f) {
  unsigned u = __float_as_uint(f);
  u += 0x7FFF + ((u >> 16) & 1);
  return (unsigned short)(u >> 16);
}
// lo16 = bf16(lo), hi16 = bf16(hi)  (RNE; verified)
__device__ __forceinline__ unsigned int cvtpk(float lo, float hi) {
  unsigned int r;
  asm("v_cvt_pk_bf16_f32 %0, %1, %2" : "=v"(r) : "v"(lo), "v"(hi));
  return r;
}

// ---- Kernel 1 (merged prep): blocks [0,288): weight fp32 -> bf16 A-frags,
//      tap-major K (k'=tap*256+c); blocks [288,1888): x NCHW fp32 -> NHWC bf16.
__global__ void prep(const float* __restrict__ w, const float* __restrict__ x,
                     unsigned short* __restrict__ wp,
                     unsigned short* __restrict__ xt) {
  __shared__ float tile[64][65];
  const int tid = threadIdx.x;
  if (blockIdx.x < PREP_W_BLOCKS) {
    const int t = blockIdx.x * 256 + tid;
    const int lane = t & 63;
    const int ocf  = (t >> 6) & 15;
    const int kb   = t >> 10;
    const int oc   = ocf * 16 + (lane & 15);
    const int k0   = kb * 32 + (lane >> 4) * 8;   // 8 consecutive k'
    const int tap  = k0 >> 8;
    const int c0   = k0 & 255;
    const float* src = w + (size_t)oc * Ktot + (size_t)c0 * KK + tap;
    short8 pk;
    #pragma unroll
    for (int e = 0; e < 8; ++e) pk[e] = (short)f2bf(src[e * KK]);
    *(short8*)(wp + (size_t)t * 8) = pk;
    return;
  }
  const int b = blockIdx.x - PREP_W_BLOCKS;       // 0..1599
  const int hw0 = (b % 100) * 64;
  const int c0  = ((b / 100) & 3) * 64;
  const int n   = b / 400;
  #pragma unroll
  for (int i = 0; i < 16; ++i) {
    const int idx = i * 256 + tid;
    const int cl = idx >> 6, hl = idx & 63;
    tile[cl][hl] = x[((size_t)(n * Cc + c0 + cl)) * HW + hw0 + hl];
  }
  __syncthreads();
  #pragma unroll
  for (int i = 0; i < 16; ++i) {
    const int idx = i * 256 + tid;
    const int hl = idx >> 6, cl = idx & 63;
    xt[((size_t)(n * HW + hw0 + hl)) * Cc + c0 + cl] = f2bf(tile[cl][hl]);
  }
}

// ---- Kernel 2: fused sampling + MFMA, 8 waves / 64 px per block ----
__global__ __launch_bounds__(512, 4) void dcn_mfma(
    const float* __restrict__ x, const float* __restrict__ offset,
    const unsigned short* __restrict__ wp,
    const unsigned short* __restrict__ xt, float* __restrict__ out) {
  __shared__ unsigned short s_col[3][PT * KC];  // 3 x 8KB, XOR-swizzled [px][k]
  __shared__ float4 s_w[KK * PT];               // masked corner weights
  __shared__ int4   s_i[KK * PT];               // corner byte offsets (hw*512)

  const int tid  = threadIdx.x;
  const int lane = tid & 63;
  const int wv   = tid >> 6;        // 8 waves; wave owns ocf {2wv, 2wv+1}

  // XCD-aware bijective swizzle: 400 blocks = 8 XCDs x 50 contiguous tiles
  const int bid  = blockIdx.x;
  const int logical = (bid & 7) * 50 + (bid >> 3);
  const int nn   = logical / 100;
  const int tile = logical - nn * 100;
  const int p0   = tile * PT;
  const char* xn = (const char*)(xt + (size_t)nn * HW * Cc);

  // ---- Phase 0: bilinear coords; masks folded into per-corner weights ----
  for (int s = tid; s < KK * PT; s += 512) {
    const int k = s / PT, p = s % PT;
    const int pp = p0 + p;
    const int oy = pp / Ww, ox = pp % Ww;
    const int ky = k / 3, kx = k % 3;
    const float offy = offset[(size_t)(nn * 18 + 2 * k    ) * HW + pp];
    const float offx = offset[(size_t)(nn * 18 + 2 * k + 1) * HW + pp];
    const float py = offy + (float)(ky + oy - 1);
    const float px = offx + (float)(kx + ox - 1);
    const float fy0 = floorf(py), fx0 = floorf(px);
    const int iy0 = (int)fy0, ix0 = (int)fx0;
    const float wy1 = py - fy0, wx1 = px - fx0;
    const float wy0 = 1.f - wy1, wx0 = 1.f - wx1;
    const bool my0 = (iy0     >= 0) & (iy0     < Hh);
    const bool my1 = (iy0 + 1 >= 0) & (iy0 + 1 < Hh);
    const bool mx0 = (ix0     >= 0) & (ix0     < Ww);
    const bool mx1 = (ix0 + 1 >= 0) & (ix0 + 1 < Ww);
    const int cy0 = min(max(iy0,     0), Hh - 1);
    const int cy1 = min(max(iy0 + 1, 0), Hh - 1);
    const int cx0 = min(max(ix0,     0), Ww - 1);
    const int cx1 = min(max(ix0 + 1, 0), Ww - 1);
    float4 w4;
    w4.x = wx0 * wy0 * ((my0 && mx0) ? 1.f : 0.f);
    w4.y = wx1 * wy0 * ((my0 && mx1) ? 1.f : 0.f);
    w4.z = wx0 * wy1 * ((my1 && mx0) ? 1.f : 0.f);
    w4.w = wx1 * wy1 * ((my1 && mx1) ? 1.f : 0.f);
    int4 i4;  // byte offsets into xt[n]: hw * 256ch * 2B
    i4.x = (cy0 * Ww + cx0) * 512;  i4.y = (cy0 * Ww + cx1) * 512;
    i4.z = (cy1 * Ww + cx0) * 512;  i4.w = (cy1 * Ww + cx1) * 512;
    s_w[s] = w4;
    s_i[s] = i4;
  }

  floatx4 acc[2][4] = {};           // 2 ocf x 4 px-frags
  const int lm = lane & 15, lg = lane >> 4;
  // Coalesced sampling map (R12): cg in low 3 lane bits.
  const int spx = tid >> 3;         // sampling pixel (0..63)
  const int cg  = tid & 7;          // channel group: 8 channels
  const int wbyte = spx * 128 + ((cg * 16) ^ ((spx & 7) << 4));
  __syncthreads();                  // once; full drain fine here

  // Named in-flight register sets (rule #20: static names).
  short8 raA, rbA, rcA, rdA, raB, rbB, rcB, rdB;          // gathers (2 sets)
  short8 fA00, fA01, fA10, fA11, fB00, fB01, fB10, fB11;  // A-frags (2 sets)

  #define ISSUE(ch, S)                                                  \
    { const int tap_ = (ch) >> 2;                                       \
      const int coff_ = (((ch) & 3) * KC + cg * 8) * 2;                 \
      const int4 i4_ = s_i[tap_ * PT + spx];                            \
      ra##S = *(const short8*)(xn + i4_.x + coff_);                     \
      rb##S = *(const short8*)(xn + i4_.y + coff_);                     \
      rc##S = *(const short8*)(xn + i4_.z + coff_);                     \
      rd##S = *(const short8*)(xn + i4_.w + coff_); }

  // Prefetch chunk ch's 4 A-fragments (2 ocf x 2 ks) into register set S.
  #define PREFA(ch, S)                                                  \
    { const unsigned short* w0_ = wp + (size_t)((ch) * 2) * (16 * 64 * 8) \
                                     + (size_t)((wv * 2) * 64 + lane) * 8; \
      f##S##00 = *(const short8*)(w0_);                                 \
      f##S##01 = *(const short8*)(w0_ + 64 * 8);                        \
      f##S##10 = *(const short8*)(w0_ + 16 * 64 * 8);                   \
      f##S##11 = *(const short8*)(w0_ + 16 * 64 * 8 + 64 * 8); }

  // float2 bilinear combine (-> v_pk_fma_f32 via ffp-contract) + cvt_pk pack.
  // (Verified correct in R16: absmax 0.03125.)
  #define FINISH(ch, S)                                                 \
    { const int tap_ = (ch) >> 2;                                       \
      const float4 w4_ = s_w[tap_ * PT + spx];                          \
      const uint4v ua_ = __builtin_bit_cast(uint4v, ra##S);             \
      const uint4v ub_ = __builtin_bit_cast(uint4v, rb##S);             \
      const uint4v uc_ = __builtin_bit_cast(uint4v, rc##S);             \
      const uint4v ud_ = __builtin_bit_cast(uint4v, rd##S);             \
      uint4v pk_;                                                       \
      _Pragma("unroll")                                                 \
      for (int r_ = 0; r_ < 4; ++r_) {                                  \
        floatx2 va_, vb_, vc_, vd_;                                     \
        va_[0] = __uint_as_float(ua_[r_] << 16);                        \
        va_[1] = __uint_as_float(ua_[r_] & 0xFFFF0000u);                \
        vb_[0] = __uint_as_float(ub_[r_] << 16);                        \
        vb_[1] = __uint_as_float(ub_[r_] & 0xFFFF0000u);                \
        vc_[0] = __uint_as_float(uc_[r_] << 16);                        \
        vc_[1] = __uint_as_float(uc_[r_] & 0xFFFF0000u);                \
        vd_[0] = __uint_as_float(ud_[r_] << 16);                        \
        vd_[1] = __uint_as_float(ud_[r_] & 0xFFFF0000u);                \
        const floatx2 v_ = w4_.x * va_ + w4_.y * vb_                    \
                         + w4_.z * vc_ + w4_.w * vd_;                   \
        pk_[r_] = cvtpk(v_[0], v_[1]);                                  \
      }                                                                 \
      *(uint4v*)((char*)s_col[(ch) % 3] + wbyte) = pk_; }

  // Pure ds_read + MFMA (A-frags preloaded in set S) + T5 setprio.
  #define MFMA_STEP(ch, S)                                              \
    { const char* base_ = (const char*)s_col[(ch) % 3];                 \
      __builtin_amdgcn_s_setprio(1);                                    \
      _Pragma("unroll")                                                 \
      for (int ks = 0; ks < 2; ++ks) {                                  \
        short8 b_[4];                                                   \
        _Pragma("unroll")                                               \
        for (int j = 0; j < 4; ++j) {                                   \
          const int px_ = j * 16 + lm;                                  \
          const int byte_ = px_ * 128 + (((ks * 64) + lg * 16) ^ ((px_ & 7) << 4)); \
          b_[j] = *(const short8*)(base_ + byte_);                      \
        }                                                               \
        const short8 a0_ = ks ? f##S##10 : f##S##00;                    \
        const short8 a1_ = ks ? f##S##11 : f##S##01;                    \
        _Pragma("unroll")                                               \
        for (int j = 0; j < 4; ++j)                                     \
          acc[0][j] = __builtin_amdgcn_mfma_f32_16x16x32_bf16(a0_, b_[j], acc[0][j], 0, 0, 0); \
        _Pragma("unroll")                                               \
        for (int j = 0; j < 4; ++j)                                     \
          acc[1][j] = __builtin_amdgcn_mfma_f32_16x16x32_bf16(a1_, b_[j], acc[1][j], 0, 0, 0); \
      }                                                                 \
      __builtin_amdgcn_s_setprio(0); }

  // ---- Prologue: buf0 + A-frags(0) ready; gathers(1) in flight ----
  PREFA(0, A);
  ISSUE(0, A);
  FINISH(0, A);          // startup stall (once)
  ISSUE(1, A);
  BARRIER_LDS();

  // ---- Main loop (2 chunks/iter). Per half: MFMA (A preloaded) ->
  //      PREFA next A (older than next gathers) -> ISSUE next gathers ->
  //      FINISH prev -> barrier.
  for (int it = 0; it < NCHUNK / 2; ++it) {
    const int ch = it * 2;
    MFMA_STEP(ch, A);
    PREFA(ch + 1, B);
    if (ch + 2 < NCHUNK) ISSUE(ch + 2, B);
    FINISH(ch + 1, A);
    BARRIER_LDS();
    MFMA_STEP(ch + 1, B);
    if (ch + 2 < NCHUNK) PREFA(ch + 2, A);
    if (ch + 3 < NCHUNK) ISSUE(ch + 3, A);
    if (ch + 2 < NCHUNK) FINISH(ch + 2, B);
    BARRIER_LDS();
  }

  // ---- Epilogue: direct stores; C/D col(px)=lane&15, row(oc)=lg*4+r ----
  #pragma unroll
  for (int f = 0; f < 2; ++f) {
    const int oc = (wv * 2 + f) * 16 + lg * 4;
    #pragma unroll
    for (int j = 0; j < 4; ++j) {
      const int px = p0 + j * 16 + lm;
      #pragma unroll
      for (int r = 0; r < 4; ++r) {
        out[(size_t)(nn * OCc + oc + r) * HW + px] = acc[f][j][r];
      }
    }
  }
}

extern "C" void kernel_launch(void* const* d_in, const int* in_sizes, int n_in,
                              void* d_out, int out_size, void* d_ws, size_t ws_size,
                              hipStream_t stream) {
  const float* x      = (const float*)d_in[0];
  const float* offset = (const float*)d_in[1];
  const float* weight = (const float*)d_in[2];
  float* out = (float*)d_out;
  unsigned short* wp = (unsigned short*)d_ws;              // 1.18 MB
  unsigned short* xt = (unsigned short*)d_ws + XT_OFF;     // 13.1 MB

  prep<<<dim3(PREP_W_BLOCKS + 1600), dim3(256), 0, stream>>>(weight, x, wp, xt);
  dcn_mfma<<<dim3(400), dim3(512), 0, stream>>>(x, offset, wp, xt, out);
}